// Round 6
// baseline (376.145 us; speedup 1.0000x reference)
//
#include <hip/hip_runtime.h>
#include <hip/hip_fp16.h>
#include <math.h>

#define N_NODES 50000
#define NPAD    50048
#define N_EDGES 800000
#define F_IN    128
#define HC      64
#define NG      128
#define NCLS    10
#define NXT     782      // ceil(N_NODES/64) row tiles
#define XCHUNK  98       // ceil(NXT/8) tiles per XCD
#define DRANGE  6250     // N_NODES / 8 dst-range per XCD group

typedef __attribute__((ext_vector_type(8))) short bfrag;   // 8 bf16 (4 VGPR)
typedef __attribute__((ext_vector_type(4))) float f32x4;
typedef _Float16 half2v __attribute__((ext_vector_type(2)));

__device__ __forceinline__ unsigned short f2bf_rne(float f) {
    unsigned u = __float_as_uint(f);
    unsigned r = u + 0x7FFF + ((u >> 16) & 1);
    return (unsigned short)(r >> 16);
}
__device__ __forceinline__ float bf2f(unsigned short h) {
    return __uint_as_float(((unsigned)h) << 16);
}

__device__ __forceinline__ float fdot2_acc(unsigned a, unsigned b, float c) {
#if __has_builtin(__builtin_amdgcn_fdot2)
    half2v ha, hb;
    __builtin_memcpy(&ha, &a, 4);
    __builtin_memcpy(&hb, &b, 4);
    return __builtin_amdgcn_fdot2(ha, hb, c, false);
#else
    __half2 ha = *(__half2*)&a, hb = *(__half2*)&b;
    return c + __low2float(ha) * __low2float(hb) + __high2float(ha) * __high2float(hb);
#endif
}

// ================= CSR build: bucket partition -> XCD-local hist/scatter =================
// Pass 0: count edges per dst-range bucket (LDS-aggregated).
__global__ __launch_bounds__(256) void bcount_kernel(const int* __restrict__ dst,
                                                     int* __restrict__ bcnt, int e) {
    __shared__ int lc[8];
    if (threadIdx.x < 8) lc[threadIdx.x] = 0;
    __syncthreads();
    for (int t = blockIdx.x * 256 + threadIdx.x; t < e; t += gridDim.x * 256)
        atomicAdd(&lc[dst[t] / DRANGE], 1);
    __syncthreads();
    if (threadIdx.x < 8 && lc[threadIdx.x] > 0) atomicAdd(&bcnt[threadIdx.x], lc[threadIdx.x]);
}

// Pass 1: prefix over the 8 bucket counts.
__global__ void boffs_kernel(const int* __restrict__ bcnt, int* __restrict__ bbase,
                             int* __restrict__ bfill) {
    int s = 0;
    for (int g = 0; g < 8; ++g) { bbase[g] = s; bfill[g] = s; s += bcnt[g]; }
    bbase[8] = s;
}

// Pass 2: partition (dst,src) pairs into contiguous bucket regions.
// Block-aggregated reservation: 8 LDS counters, one global atomicAdd per bucket per chunk.
__global__ __launch_bounds__(256) void bpart_kernel(const int* __restrict__ src,
                                                    const int* __restrict__ dst,
                                                    int* __restrict__ bfill,
                                                    int2* __restrict__ ebuf, int e) {
    __shared__ int lcnt[8];
    __shared__ int lbase[8];
    for (int base = blockIdx.x * 256; base < e; base += gridDim.x * 256) {
        int t = base + threadIdx.x;
        int d = 0, s = 0, b = -1;
        if (t < e) { d = dst[t]; s = src[t]; b = d / DRANGE; }
        if (threadIdx.x < 8) lcnt[threadIdx.x] = 0;
        __syncthreads();
        int rank = (b >= 0) ? atomicAdd(&lcnt[b], 1) : 0;
        __syncthreads();
        if (threadIdx.x < 8 && lcnt[threadIdx.x] > 0)
            lbase[threadIdx.x] = atomicAdd(&bfill[threadIdx.x], lcnt[threadIdx.x]);
        __syncthreads();
        if (b >= 0) ebuf[lbase[b] + rank] = make_int2(d, s);
        __syncthreads();
    }
}

// Pass 3: per-node histogram reading only the local bucket (atomics XCD-local).
__global__ __launch_bounds__(256) void hist_b_kernel(const int2* __restrict__ ebuf,
                                                     const int* __restrict__ bbase,
                                                     int* __restrict__ counts) {
    int grp = blockIdx.x & 7;
    int nb = gridDim.x >> 3, slot = blockIdx.x >> 3;
    int lo = bbase[grp], hiE = bbase[grp + 1];
    for (int t = lo + slot * 256 + threadIdx.x; t < hiE; t += nb * 256)
        atomicAdd(&counts[ebuf[t].x], 1);
}

// Pass 5 (after scan): scatter src ids, reading only the local bucket.
__global__ __launch_bounds__(256) void scatter_b_kernel(const int2* __restrict__ ebuf,
                                                        const int* __restrict__ bbase,
                                                        int* __restrict__ fillp,
                                                        int* __restrict__ col_src) {
    int grp = blockIdx.x & 7;
    int nb = gridDim.x >> 3, slot = blockIdx.x >> 3;
    int lo = bbase[grp], hiE = bbase[grp + 1];
    for (int t = lo + slot * 256 + threadIdx.x; t < hiE; t += nb * 256) {
        int2 p = ebuf[t];
        int pos = atomicAdd(&fillp[p.x], 1);
        col_src[pos] = p.y;
    }
}

__global__ __launch_bounds__(256) void scanA_kernel(const int* __restrict__ counts,
                                                    int* __restrict__ excl,
                                                    int* __restrict__ bsum, int n) {
    int tid = threadIdx.x, bid = blockIdx.x;
    int i = bid * 256 + tid;
    int v = (i < n) ? counts[i] : 0;
    int lane = tid & 63, wid = tid >> 6;
    int sc = v;
    #pragma unroll
    for (int off = 1; off < 64; off <<= 1) {
        int t = __shfl_up(sc, off, 64);
        if (lane >= off) sc += t;
    }
    __shared__ int ws[4];
    if (lane == 63) ws[wid] = sc;
    __syncthreads();
    int add = 0;
    #pragma unroll
    for (int k = 0; k < 4; ++k) if (k < wid) add += ws[k];
    int incl = sc + add;
    if (i < n) excl[i] = incl - v;
    if (tid == 255) bsum[bid] = incl;
}

__global__ __launch_bounds__(256) void scanB_kernel(const int* __restrict__ bsum,
                                                    int* __restrict__ boff, int nb) {
    int tid = threadIdx.x;
    int v = (tid < nb) ? bsum[tid] : 0;
    int lane = tid & 63, wid = tid >> 6;
    int sc = v;
    #pragma unroll
    for (int off = 1; off < 64; off <<= 1) {
        int t = __shfl_up(sc, off, 64);
        if (lane >= off) sc += t;
    }
    __shared__ int ws[4];
    if (lane == 63) ws[wid] = sc;
    __syncthreads();
    int add = 0;
    #pragma unroll
    for (int k = 0; k < 4; ++k) if (k < wid) add += ws[k];
    if (tid < nb) boff[tid] = sc + add - v;
}

__global__ __launch_bounds__(256) void scanC_kernel(const int* __restrict__ excl,
                                                    const int* __restrict__ boff,
                                                    int* __restrict__ row_ptr,
                                                    int* __restrict__ fillp, int n) {
    int i = blockIdx.x * 256 + threadIdx.x;
    if (i < n) {
        int r = excl[i] + boff[i >> 8];
        row_ptr[i] = r;
        fillp[i] = r;
    }
    if (i == n) row_ptr[n] = N_EDGES;
}

// ---------------- fp32 -> bf16 hi/lo split (x input) ----------------
__global__ void split_kernel(const float* __restrict__ in, unsigned short* __restrict__ hi,
                             unsigned short* __restrict__ lo, int n4) {
    int t = blockIdx.x * blockDim.x + threadIdx.x;
    if (t >= n4) return;
    float4 f = ((const float4*)in)[t];
    unsigned short h[4], l[4];
    float ff[4] = {f.x, f.y, f.z, f.w};
    #pragma unroll
    for (int i = 0; i < 4; ++i) {
        h[i] = f2bf_rne(ff[i]);
        l[i] = f2bf_rne(ff[i] - bf2f(h[i]));
    }
    ((ushort4*)hi)[t] = make_ushort4(h[0], h[1], h[2], h[3]);
    ((ushort4*)lo)[t] = make_ushort4(l[0], l[1], l[2], l[3]);
}

// ---------------- W [K][64] fp32 -> transposed bf16 hi/lo [mat][64][K] ----------------
__global__ void wconv_kernel(const float* __restrict__ W0, const float* __restrict__ W1,
                             const float* __restrict__ W2, const float* __restrict__ W3,
                             int K, unsigned short* __restrict__ wt_hi,
                             unsigned short* __restrict__ wt_lo) {
    int t = blockIdx.x * blockDim.x + threadIdx.x;
    int per = K * 64;
    if (t >= 4 * per) return;
    int mat = t / per, r = t - mat * per;
    int k = r >> 6, c = r & 63;
    const float* W = (mat == 0) ? W0 : (mat == 1) ? W1 : (mat == 2) ? W2 : W3;
    float f = W[k * 64 + c];
    unsigned short h = f2bf_rne(f);
    unsigned short l = f2bf_rne(f - bf2f(h));
    int idx = mat * per + c * K + k;
    wt_hi[idx] = h;
    wt_lo[idx] = l;
}

// ---------------- split-bf16 MFMA GEMM ----------------
// y=0 -> qp16 fp16, y=3 -> sf fp32, y=1 -> kvpk k-block fp16, y=2 -> kvpk v-block fp16
__global__ __launch_bounds__(256) void mfma_gemm_kernel(
    const unsigned short* __restrict__ A_hi, const unsigned short* __restrict__ A_lo,
    const unsigned short* __restrict__ Wt_hi, const unsigned short* __restrict__ Wt_lo,
    const float* __restrict__ b0, const float* __restrict__ b1,
    const float* __restrict__ b2, const float* __restrict__ b3,
    unsigned short* __restrict__ qp16, float* __restrict__ sf,
    unsigned short* __restrict__ kvpk,
    int M, int K)
{
    int bid = blockIdx.x;
    int xcd = bid & 7;
    int slot = bid >> 3;
    int xt = xcd * XCHUNK + (slot >> 2);
    int y = slot & 3;
    if (xt >= NXT) return;
    int row0 = xt * 64;

    extern __shared__ char smem[];
    const int tileU = 64 * K;
    unsigned short* sA_hi = (unsigned short*)smem;
    unsigned short* sA_lo = sA_hi + tileU;
    unsigned short* sB_hi = sA_lo + tileU;
    unsigned short* sB_lo = sB_hi + tileU;

    int tid = threadIdx.x;
    int cpr = K >> 3;
    int total = 64 * cpr;
    const bfrag* gAh = (const bfrag*)(A_hi + (size_t)row0 * K);
    const bfrag* gAl = (const bfrag*)(A_lo + (size_t)row0 * K);
    const bfrag* gBh = (const bfrag*)(Wt_hi + (size_t)y * tileU);
    const bfrag* gBl = (const bfrag*)(Wt_lo + (size_t)y * tileU);
    for (int t = tid; t < total; t += 256) {
        int row = t / cpr, cs = t - row * cpr;
        int dstB = row * (K * 2) + ((cs * 16) ^ ((row & 7) << 4));
        *(bfrag*)((char*)sA_hi + dstB) = gAh[t];
        *(bfrag*)((char*)sA_lo + dstB) = gAl[t];
        *(bfrag*)((char*)sB_hi + dstB) = gBh[t];
        *(bfrag*)((char*)sB_lo + dstB) = gBl[t];
    }
    __syncthreads();

    int w = tid >> 6, lane = tid & 63, lr = lane & 15, kq = lane >> 4;
    f32x4 acc[4];
    #pragma unroll
    for (int f = 0; f < 4; ++f) acc[f] = (f32x4){0.f, 0.f, 0.f, 0.f};

    int arow = w * 16 + lr;
    int abase = arow * (K * 2);
    int aswz = (arow & 7) << 4;
    for (int ks = 0; ks < K; ks += 32) {
        int kb = ks * 2 + kq * 16;
        bfrag ah = *(const bfrag*)((const char*)sA_hi + abase + (kb ^ aswz));
        bfrag al = *(const bfrag*)((const char*)sA_lo + abase + (kb ^ aswz));
        #pragma unroll
        for (int f = 0; f < 4; ++f) {
            int brow = f * 16 + lr;
            int boff = brow * (K * 2) + (kb ^ ((brow & 7) << 4));
            bfrag bh = *(const bfrag*)((const char*)sB_hi + boff);
            bfrag bl = *(const bfrag*)((const char*)sB_lo + boff);
            acc[f] = __builtin_amdgcn_mfma_f32_16x16x32_bf16(ah, bh, acc[f], 0, 0, 0);
            acc[f] = __builtin_amdgcn_mfma_f32_16x16x32_bf16(ah, bl, acc[f], 0, 0, 0);
            acc[f] = __builtin_amdgcn_mfma_f32_16x16x32_bf16(al, bh, acc[f], 0, 0, 0);
        }
    }

    const float* bias = (y == 0) ? b0 : (y == 1) ? b1 : (y == 2) ? b2 : b3;
    if (y == 3) {
        #pragma unroll
        for (int f = 0; f < 4; ++f) {
            float bv = bias[f * 16 + lr];
            #pragma unroll
            for (int r = 0; r < 4; ++r) {
                int gr = row0 + w * 16 + kq * 4 + r;
                if (gr < M) sf[(size_t)gr * 64 + f * 16 + lr] = acc[f][r] + bv;
            }
        }
    } else if (y == 0) {
        #pragma unroll
        for (int f = 0; f < 4; ++f) {
            float bv = bias[f * 16 + lr];
            #pragma unroll
            for (int r = 0; r < 4; ++r) {
                int gr = row0 + w * 16 + kq * 4 + r;
                if (gr < M)
                    qp16[(size_t)gr * 64 + f * 16 + lr] =
                        __half_as_ushort(__float2half_rn(acc[f][r] + bv));
            }
        }
    } else {
        int off = (y == 1) ? 0 : 64;   // k-block then v-block
        #pragma unroll
        for (int f = 0; f < 4; ++f) {
            float bv = bias[f * 16 + lr];
            #pragma unroll
            for (int r = 0; r < 4; ++r) {
                int gr = row0 + w * 16 + kq * 4 + r;
                if (gr < M)
                    kvpk[(size_t)gr * 128 + off + f * 16 + lr] =
                        __half_as_ushort(__float2half_rn(acc[f][r] + bv));
            }
        }
    }
}

// ---------------- attention: wave per dst node, lane = (head, edge-slot) ----------------
__global__ __launch_bounds__(256) void attn_kernel(
    const unsigned short* __restrict__ qp, const float* __restrict__ sf,
    const uint4* __restrict__ kv4,
    const int* __restrict__ row_ptr, const int* __restrict__ col_src,
    float* __restrict__ hout,
    unsigned short* __restrict__ h_hi, unsigned short* __restrict__ h_lo,
    int n, int mode)
{
    __shared__ float lds[4][64 * 17];
    int node = (int)((blockIdx.x * (size_t)blockDim.x + threadIdx.x) >> 6);
    int lane = threadIdx.x & 63;
    int wl = threadIdx.x >> 6;
    if (node >= n) return;
    int h = lane >> 4, j = lane & 15;

    const uint4* q4 = (const uint4*)(qp + (size_t)node * 64 + h * 16);
    uint4 qa = q4[0], qb = q4[1];

    int e0 = row_ptr[node], e1 = row_ptr[node + 1];
    float acc[16];
    #pragma unroll
    for (int c = 0; c < 16; ++c) acc[c] = 0.f;
    float dsum = 0.f;

    for (int eb = e0; eb < e1; eb += 16) {
        int e = eb + j;
        int ec = (e < e1) ? e : (e1 - 1);
        int src = col_src[ec];
        const uint4* kvr = kv4 + (size_t)src * 16 + h * 2;
        uint4 ka = kvr[0], kb = kvr[1];
        uint4 va = kvr[8], vb = kvr[9];
        float s = 0.f;
        s = fdot2_acc(qa.x, ka.x, s);
        s = fdot2_acc(qa.y, ka.y, s);
        s = fdot2_acc(qa.z, ka.z, s);
        s = fdot2_acc(qa.w, ka.w, s);
        s = fdot2_acc(qb.x, kb.x, s);
        s = fdot2_acc(qb.y, kb.y, s);
        s = fdot2_acc(qb.z, kb.z, s);
        s = fdot2_acc(qb.w, kb.w, s);
        float p = (e < e1) ? __expf(s * 0.25f) : 0.f;
        dsum += p;
        unsigned uv[8] = {va.x, va.y, va.z, va.w, vb.x, vb.y, vb.z, vb.w};
        #pragma unroll
        for (int i = 0; i < 8; ++i) {
            __half2 hv = *(__half2*)&uv[i];
            acc[2 * i]     += p * __low2float(hv);
            acc[2 * i + 1] += p * __high2float(hv);
        }
    }

    dsum += __shfl_xor(dsum, 1, 64);
    dsum += __shfl_xor(dsum, 2, 64);
    dsum += __shfl_xor(dsum, 4, 64);
    dsum += __shfl_xor(dsum, 8, 64);
    float inv = 1.f / (dsum + 1e-16f);

    float* L = lds[wl];
    int wb = lane * 17;
    #pragma unroll
    for (int c = 0; c < 16; ++c) L[wb + c] = acc[c];
    __builtin_amdgcn_wave_barrier();
    float sum = 0.f;
    int rb = (h * 16) * 17 + j;
    #pragma unroll
    for (int jj = 0; jj < 16; ++jj) sum += L[rb + jj * 17];

    float outv = sum * inv + sf[(size_t)node * 64 + lane];
    if (mode == 1) {
        outv = fmaxf(outv, 0.f);
        unsigned short hh = f2bf_rne(outv);
        unsigned short ll = f2bf_rne(outv - bf2f(hh));
        h_hi[(size_t)node * 64 + lane] = hh;
        h_lo[(size_t)node * 64 + lane] = ll;
    } else {
        hout[(size_t)node * 64 + lane] = outv;
    }
}

// ---------------- pooling + head ----------------
__global__ void graph_ranges_kernel(const int* __restrict__ bm, int* __restrict__ gstart,
                                    int n, int g) {
    int t = blockIdx.x * blockDim.x + threadIdx.x;
    if (t > g) return;
    if (t == g) { gstart[g] = n; return; }
    int lo = 0, hi = n;
    while (lo < hi) { int mid = (lo + hi) >> 1; if (bm[mid] < t) lo = mid + 1; else hi = mid; }
    gstart[t] = lo;
}

__global__ __launch_bounds__(256) void pool_kernel(
    const float* __restrict__ h, const int* __restrict__ gstart,
    float* __restrict__ pooled)
{
    int g = blockIdx.x;
    int c = threadIdx.x & 63, sub = threadIdx.x >> 6;
    int s = gstart[g], e = gstart[g + 1];
    float sum = 0.f;
    for (int i = s + sub; i < e; i += 4) sum += h[(size_t)i * 64 + c];
    __shared__ float tmp[256];
    tmp[threadIdx.x] = sum;
    __syncthreads();
    if (sub == 0) {
        sum = tmp[c] + tmp[c + 64] + tmp[c + 128] + tmp[c + 192];
        int cnt = e - s;
        pooled[g * 64 + c] = sum / fmaxf((float)cnt, 1.0f);
    }
}

__global__ void head_kernel(const float* __restrict__ pooled,
                            const float* __restrict__ Wl, const float* __restrict__ bl,
                            float* __restrict__ out)
{
    int g = blockIdx.x;
    int lane = threadIdx.x;
    __shared__ float pl[64];
    pl[lane] = pooled[g * 64 + lane];
    __syncthreads();
    float logit = -INFINITY;
    if (lane < NCLS) {
        float acc = bl[lane];
        for (int k = 0; k < 64; ++k) acc += pl[k] * Wl[k * NCLS + lane];
        logit = acc;
    }
    float mx = logit;
    mx = fmaxf(mx, __shfl_xor(mx, 1, 64));
    mx = fmaxf(mx, __shfl_xor(mx, 2, 64));
    mx = fmaxf(mx, __shfl_xor(mx, 4, 64));
    mx = fmaxf(mx, __shfl_xor(mx, 8, 64));
    float ex = (lane < NCLS) ? __expf(logit - mx) : 0.f;
    float sm = ex;
    sm += __shfl_xor(sm, 1, 64);
    sm += __shfl_xor(sm, 2, 64);
    sm += __shfl_xor(sm, 4, 64);
    sm += __shfl_xor(sm, 8, 64);
    if (lane < NCLS) out[g * NCLS + lane] = ex / sm;
}

// ---------------- launch ----------------
extern "C" void kernel_launch(void* const* d_in, const int* in_sizes, int n_in,
                              void* d_out, int out_size, void* d_ws, size_t ws_size,
                              hipStream_t stream) {
    const float* x  = (const float*)d_in[0];
    const int*   ei = (const int*)d_in[1];
    const int*   bm = (const int*)d_in[2];
    const float* W1[4] = {(const float*)d_in[3], (const float*)d_in[5], (const float*)d_in[7], (const float*)d_in[9]};
    const float* B1[4] = {(const float*)d_in[4], (const float*)d_in[6], (const float*)d_in[8], (const float*)d_in[10]};
    const float* W2[4] = {(const float*)d_in[11], (const float*)d_in[13], (const float*)d_in[15], (const float*)d_in[17]};
    const float* B2[4] = {(const float*)d_in[12], (const float*)d_in[14], (const float*)d_in[16], (const float*)d_in[18]};
    const float* W3[4] = {(const float*)d_in[19], (const float*)d_in[21], (const float*)d_in[23], (const float*)d_in[25]};
    const float* B3[4] = {(const float*)d_in[20], (const float*)d_in[22], (const float*)d_in[24], (const float*)d_in[26]};
    const float* Wl = (const float*)d_in[27];
    const float* bl = (const float*)d_in[28];
    float* outp = (float*)d_out;

    // workspace layout
    float* sf     = (float*)d_ws;                                 // NPAD*64 f32
    float* hf     = sf + (size_t)NPAD * 64;                       // NPAD*64 f32
    float* pooled = hf + (size_t)NPAD * 64;                       // NG*64
    unsigned short* qp16 = (unsigned short*)(pooled + NG * 64);   // NPAD*64 fp16
    unsigned short* kvpk = qp16 + (size_t)NPAD * 64;              // NPAD*128 fp16
    unsigned short* xs_hi = kvpk + (size_t)NPAD * 128;            // NPAD*128
    unsigned short* xs_lo = xs_hi + (size_t)NPAD * 128;
    unsigned short* hs_hi = xs_lo + (size_t)NPAD * 128;           // NPAD*64
    unsigned short* hs_lo = hs_hi + (size_t)NPAD * 64;
    unsigned short* wt_hi = hs_lo + (size_t)NPAD * 64;            // 3 * 4*64*128
    unsigned short* wt_lo = wt_hi + 3 * 4 * 64 * 128;
    int* row_ptr = (int*)(wt_lo + 3 * 4 * 64 * 128);              // N+1
    int* fillp   = row_ptr + (N_NODES + 1);                       // N
    int* bcnt    = fillp + N_NODES;                               // 16 (memset with counts)
    int* counts  = bcnt + 16;                                     // N
    int* excl    = counts + N_NODES;                              // N
    int* bsum    = excl + N_NODES;                                // 256
    int* boff    = bsum + 256;                                    // 256
    int* bbase   = boff + 256;                                    // 9
    int* bfill   = bbase + 16;                                    // 8
    int* col_src = bfill + 16;                                    // E
    int2* ebuf   = (int2*)(col_src + N_EDGES);                    // E int2
    int* gstart  = (int*)(ebuf + N_EDGES);                        // NG+1

    const int* srcp = ei;
    const int* dstp = ei + N_EDGES;

    // CSR build: bucket partition, then XCD-local hist + scatter
    hipMemsetAsync(bcnt, 0, (16 + N_NODES) * sizeof(int), stream);   // bcnt + counts
    bcount_kernel<<<1024, 256, 0, stream>>>(dstp, bcnt, N_EDGES);
    boffs_kernel<<<1, 1, 0, stream>>>(bcnt, bbase, bfill);
    bpart_kernel<<<2048, 256, 0, stream>>>(srcp, dstp, bfill, ebuf, N_EDGES);
    hist_b_kernel<<<1024, 256, 0, stream>>>(ebuf, bbase, counts);
    scanA_kernel<<<196, 256, 0, stream>>>(counts, excl, bsum, N_NODES);
    scanB_kernel<<<1, 256, 0, stream>>>(bsum, boff, 196);
    scanC_kernel<<<196, 256, 0, stream>>>(excl, boff, row_ptr, fillp, N_NODES);
    scatter_b_kernel<<<1024, 256, 0, stream>>>(ebuf, bbase, fillp, col_src);

    // conversions
    int n4x = N_NODES * F_IN / 4;
    split_kernel<<<(n4x + 255) / 256, 256, 0, stream>>>(x, xs_hi, xs_lo, n4x);
    wconv_kernel<<<(4 * 128 * 64 + 255) / 256, 256, 0, stream>>>(
        W1[0], W1[1], W1[2], W1[3], F_IN, wt_hi + 0 * 4 * 64 * 128, wt_lo + 0 * 4 * 64 * 128);
    wconv_kernel<<<(4 * 64 * 64 + 255) / 256, 256, 0, stream>>>(
        W2[0], W2[1], W2[2], W2[3], HC, wt_hi + 1 * 4 * 64 * 128, wt_lo + 1 * 4 * 64 * 128);
    wconv_kernel<<<(4 * 64 * 64 + 255) / 256, 256, 0, stream>>>(
        W3[0], W3[1], W3[2], W3[3], HC, wt_hi + 2 * 4 * 64 * 128, wt_lo + 2 * 4 * 64 * 128);

    int ggrid = 8 * XCHUNK * 4;
    int agrid = (N_NODES + 3) / 4;
    size_t smem1 = (size_t)4 * 64 * F_IN * 2;
    size_t smem2 = (size_t)4 * 64 * HC * 2;

    // layer 1
    mfma_gemm_kernel<<<ggrid, 256, smem1, stream>>>(xs_hi, xs_lo,
        wt_hi + 0 * 4 * 64 * 128, wt_lo + 0 * 4 * 64 * 128,
        B1[0], B1[1], B1[2], B1[3], qp16, sf, kvpk, N_NODES, F_IN);
    attn_kernel<<<agrid, 256, 0, stream>>>(qp16, sf, (const uint4*)kvpk, row_ptr, col_src,
                                           nullptr, hs_hi, hs_lo, N_NODES, 1);
    // layer 2
    mfma_gemm_kernel<<<ggrid, 256, smem2, stream>>>(hs_hi, hs_lo,
        wt_hi + 1 * 4 * 64 * 128, wt_lo + 1 * 4 * 64 * 128,
        B2[0], B2[1], B2[2], B2[3], qp16, sf, kvpk, N_NODES, HC);
    attn_kernel<<<agrid, 256, 0, stream>>>(qp16, sf, (const uint4*)kvpk, row_ptr, col_src,
                                           nullptr, hs_hi, hs_lo, N_NODES, 1);
    // layer 3
    mfma_gemm_kernel<<<ggrid, 256, smem2, stream>>>(hs_hi, hs_lo,
        wt_hi + 2 * 4 * 64 * 128, wt_lo + 2 * 4 * 64 * 128,
        B3[0], B3[1], B3[2], B3[3], qp16, sf, kvpk, N_NODES, HC);
    attn_kernel<<<agrid, 256, 0, stream>>>(qp16, sf, (const uint4*)kvpk, row_ptr, col_src,
                                           hf, nullptr, nullptr, N_NODES, 0);

    // pooling + head
    graph_ranges_kernel<<<1, 256, 0, stream>>>(bm, gstart, N_NODES, NG);
    pool_kernel<<<NG, 256, 0, stream>>>(hf, gstart, pooled);
    head_kernel<<<NG, 64, 0, stream>>>(pooled, Wl, bl, outp);
}

// Round 7
// 315.352 us; speedup vs baseline: 1.1928x; 1.1928x over previous
//
#include <hip/hip_runtime.h>
#include <hip/hip_fp16.h>
#include <math.h>

#define N_NODES 50000
#define NPAD    50048
#define N_EDGES 800000
#define F_IN    128
#define HC      64
#define NG      128
#define NCLS    10
#define NXT     782      // ceil(N_NODES/64) row tiles
#define XCHUNK  98       // ceil(NXT/8) tiles per XCD
#define DRANGE  6250     // N_NODES / 8 dst-range per XCD group
#define BLSCALE 4096.0f  // B low-residual scale (keeps it in fp16 normal range)

typedef __attribute__((ext_vector_type(8))) _Float16 f16x8;  // 8 fp16 (4 VGPR)
typedef __attribute__((ext_vector_type(4))) float f32x4;
typedef _Float16 half2v __attribute__((ext_vector_type(2)));

__device__ __forceinline__ float fdot2_acc(unsigned a, unsigned b, float c) {
#if __has_builtin(__builtin_amdgcn_fdot2)
    half2v ha, hb;
    __builtin_memcpy(&ha, &a, 4);
    __builtin_memcpy(&hb, &b, 4);
    return __builtin_amdgcn_fdot2(ha, hb, c, false);
#else
    __half2 ha = *(__half2*)&a, hb = *(__half2*)&b;
    return c + __low2float(ha) * __low2float(hb) + __high2float(ha) * __high2float(hb);
#endif
}

// ================= CSR build: dst-range partitioned + non-temporal edge streams ========
// blocks with (blockIdx.x & 7 == g) own dst range [g*DRANGE,(g+1)*DRANGE): with round-robin
// block->XCD dispatch, group g's atomics + col_src lines stay in ONE XCD's L2. The edge-list
// streams use non-temporal loads so they don't evict the partially-filled col_src lines
// (R5 evidence: WRITE_SIZE 31 MB vs 3.2 MB ideal = L2 pollution from the 6.4 MB streams).
__global__ __launch_bounds__(256) void hist_part_kernel(const int* __restrict__ dst,
                                                        int* __restrict__ counts, int e) {
    int grp = blockIdx.x & 7;
    int nb = gridDim.x >> 3;
    int slot = blockIdx.x >> 3;
    int lo = grp * DRANGE, hi = lo + DRANGE;
    for (int t = slot * 256 + threadIdx.x; t < e; t += nb * 256) {
        int d = __builtin_nontemporal_load(&dst[t]);
        if (d >= lo && d < hi) atomicAdd(&counts[d], 1);
    }
}

__global__ __launch_bounds__(256) void scatter_part_kernel(const int* __restrict__ src,
                                                           const int* __restrict__ dst,
                                                           int* __restrict__ fillp,
                                                           int* __restrict__ col_src, int e) {
    int grp = blockIdx.x & 7;
    int nb = gridDim.x >> 3;
    int slot = blockIdx.x >> 3;
    int lo = grp * DRANGE, hi = lo + DRANGE;
    for (int t = slot * 256 + threadIdx.x; t < e; t += nb * 256) {
        int d = __builtin_nontemporal_load(&dst[t]);
        if (d >= lo && d < hi) {
            int s = __builtin_nontemporal_load(&src[t]);
            int pos = atomicAdd(&fillp[d], 1);
            col_src[pos] = s;
        }
    }
}

__global__ __launch_bounds__(256) void scanA_kernel(const int* __restrict__ counts,
                                                    int* __restrict__ excl,
                                                    int* __restrict__ bsum, int n) {
    int tid = threadIdx.x, bid = blockIdx.x;
    int i = bid * 256 + tid;
    int v = (i < n) ? counts[i] : 0;
    int lane = tid & 63, wid = tid >> 6;
    int sc = v;
    #pragma unroll
    for (int off = 1; off < 64; off <<= 1) {
        int t = __shfl_up(sc, off, 64);
        if (lane >= off) sc += t;
    }
    __shared__ int ws[4];
    if (lane == 63) ws[wid] = sc;
    __syncthreads();
    int add = 0;
    #pragma unroll
    for (int k = 0; k < 4; ++k) if (k < wid) add += ws[k];
    int incl = sc + add;
    if (i < n) excl[i] = incl - v;
    if (tid == 255) bsum[bid] = incl;
}

__global__ __launch_bounds__(256) void scanB_kernel(const int* __restrict__ bsum,
                                                    int* __restrict__ boff, int nb) {
    int tid = threadIdx.x;
    int v = (tid < nb) ? bsum[tid] : 0;
    int lane = tid & 63, wid = tid >> 6;
    int sc = v;
    #pragma unroll
    for (int off = 1; off < 64; off <<= 1) {
        int t = __shfl_up(sc, off, 64);
        if (lane >= off) sc += t;
    }
    __shared__ int ws[4];
    if (lane == 63) ws[wid] = sc;
    __syncthreads();
    int add = 0;
    #pragma unroll
    for (int k = 0; k < 4; ++k) if (k < wid) add += ws[k];
    if (tid < nb) boff[tid] = sc + add - v;
}

__global__ __launch_bounds__(256) void scanC_kernel(const int* __restrict__ excl,
                                                    const int* __restrict__ boff,
                                                    int* __restrict__ row_ptr,
                                                    int* __restrict__ fillp, int n) {
    int i = blockIdx.x * 256 + threadIdx.x;
    if (i < n) {
        int r = excl[i] + boff[i >> 8];
        row_ptr[i] = r;
        fillp[i] = r;
    }
    if (i == n) row_ptr[n] = N_EDGES;
}

// ---------------- fp32 -> fp16 cast (x input) ----------------
__global__ void castx_kernel(const float* __restrict__ in, unsigned short* __restrict__ o,
                             int n4) {
    int t = blockIdx.x * blockDim.x + threadIdx.x;
    if (t >= n4) return;
    float4 f = ((const float4*)in)[t];
    ushort4 u;
    u.x = __half_as_ushort(__float2half_rn(f.x));
    u.y = __half_as_ushort(__float2half_rn(f.y));
    u.z = __half_as_ushort(__float2half_rn(f.z));
    u.w = __half_as_ushort(__float2half_rn(f.w));
    ((ushort4*)o)[t] = u;
}

// ---------------- W [K][64] fp32 -> transposed fp16 hi + scaled residual [mat][64][K] -----
__global__ void wconv_kernel(const float* __restrict__ W0, const float* __restrict__ W1,
                             const float* __restrict__ W2, const float* __restrict__ W3,
                             int K, unsigned short* __restrict__ wt_h,
                             unsigned short* __restrict__ wt_l) {
    int t = blockIdx.x * blockDim.x + threadIdx.x;
    int per = K * 64;
    if (t >= 4 * per) return;
    int mat = t / per, r = t - mat * per;
    int k = r >> 6, c = r & 63;
    const float* W = (mat == 0) ? W0 : (mat == 1) ? W1 : (mat == 2) ? W2 : W3;
    float f = W[k * 64 + c];
    __half h = __float2half_rn(f);
    float resid = (f - __half2float(h)) * BLSCALE;
    int idx = mat * per + c * K + k;
    wt_h[idx] = __half_as_ushort(h);
    wt_l[idx] = __half_as_ushort(__float2half_rn(resid));
}

// ---------------- fp16 MFMA GEMM (2-pass: A*Bh + (A*Bl)/BLSCALE) ----------------
// y=0 -> qp16 fp16, y=3 -> sf fp32, y=1 -> kvpk k-block fp16, y=2 -> kvpk v-block fp16
__global__ __launch_bounds__(256) void mfma_gemm_kernel(
    const unsigned short* __restrict__ A16,
    const unsigned short* __restrict__ Wt_h, const unsigned short* __restrict__ Wt_l,
    const float* __restrict__ b0, const float* __restrict__ b1,
    const float* __restrict__ b2, const float* __restrict__ b3,
    unsigned short* __restrict__ qp16, float* __restrict__ sf,
    unsigned short* __restrict__ kvpk,
    int M, int K)
{
    int bid = blockIdx.x;
    int xcd = bid & 7;
    int slot = bid >> 3;
    int xt = xcd * XCHUNK + (slot >> 2);
    int y = slot & 3;
    if (xt >= NXT) return;
    int row0 = xt * 64;

    extern __shared__ char smem[];
    const int tileB = 64 * K * 2;                 // bytes per tile
    char* sA  = smem;
    char* sBh = smem + tileB;
    char* sBl = smem + 2 * tileB;

    int tid = threadIdx.x;
    int cpr = K >> 3;                             // 16B chunks per row
    int total = 64 * cpr;
    const f16x8* gA  = (const f16x8*)(A16 + (size_t)row0 * K);
    const f16x8* gBh = (const f16x8*)(Wt_h + (size_t)y * 64 * K);
    const f16x8* gBl = (const f16x8*)(Wt_l + (size_t)y * 64 * K);
    for (int t = tid; t < total; t += 256) {
        int row = t / cpr, cs = t - row * cpr;
        int dstB = row * (K * 2) + ((cs * 16) ^ ((row & 7) << 4));
        *(f16x8*)(sA + dstB)  = gA[t];
        *(f16x8*)(sBh + dstB) = gBh[t];
        *(f16x8*)(sBl + dstB) = gBl[t];
    }
    __syncthreads();

    int w = tid >> 6, lane = tid & 63, lr = lane & 15, kq = lane >> 4;
    f32x4 accH[4], accL[4];
    #pragma unroll
    for (int f = 0; f < 4; ++f) {
        accH[f] = (f32x4){0.f, 0.f, 0.f, 0.f};
        accL[f] = (f32x4){0.f, 0.f, 0.f, 0.f};
    }

    int arow = w * 16 + lr;
    int abase = arow * (K * 2);
    int aswz = (arow & 7) << 4;
    for (int ks = 0; ks < K; ks += 32) {
        int kb = ks * 2 + kq * 16;
        f16x8 a = *(const f16x8*)(sA + abase + (kb ^ aswz));
        #pragma unroll
        for (int f = 0; f < 4; ++f) {
            int brow = f * 16 + lr;
            int boff = brow * (K * 2) + (kb ^ ((brow & 7) << 4));
            f16x8 bh = *(const f16x8*)(sBh + boff);
            f16x8 bl = *(const f16x8*)(sBl + boff);
            accH[f] = __builtin_amdgcn_mfma_f32_16x16x32_f16(a, bh, accH[f], 0, 0, 0);
            accL[f] = __builtin_amdgcn_mfma_f32_16x16x32_f16(a, bl, accL[f], 0, 0, 0);
        }
    }

    const float* bias = (y == 0) ? b0 : (y == 1) ? b1 : (y == 2) ? b2 : b3;
    const float inv = 1.0f / BLSCALE;
    if (y == 3) {
        #pragma unroll
        for (int f = 0; f < 4; ++f) {
            float bv = bias[f * 16 + lr];
            #pragma unroll
            for (int r = 0; r < 4; ++r) {
                int gr = row0 + w * 16 + kq * 4 + r;
                if (gr < M) sf[(size_t)gr * 64 + f * 16 + lr] = accH[f][r] + accL[f][r] * inv + bv;
            }
        }
    } else if (y == 0) {
        #pragma unroll
        for (int f = 0; f < 4; ++f) {
            float bv = bias[f * 16 + lr];
            #pragma unroll
            for (int r = 0; r < 4; ++r) {
                int gr = row0 + w * 16 + kq * 4 + r;
                if (gr < M)
                    qp16[(size_t)gr * 64 + f * 16 + lr] =
                        __half_as_ushort(__float2half_rn(accH[f][r] + accL[f][r] * inv + bv));
            }
        }
    } else {
        int off = (y == 1) ? 0 : 64;   // k-block then v-block
        #pragma unroll
        for (int f = 0; f < 4; ++f) {
            float bv = bias[f * 16 + lr];
            #pragma unroll
            for (int r = 0; r < 4; ++r) {
                int gr = row0 + w * 16 + kq * 4 + r;
                if (gr < M)
                    kvpk[(size_t)gr * 128 + off + f * 16 + lr] =
                        __half_as_ushort(__float2half_rn(accH[f][r] + accL[f][r] * inv + bv));
            }
        }
    }
}

// ---------------- attention: wave per dst node, lane = (head, edge-slot) ----------------
__global__ __launch_bounds__(256) void attn_kernel(
    const unsigned short* __restrict__ qp, const float* __restrict__ sf,
    const uint4* __restrict__ kv4,
    const int* __restrict__ row_ptr, const int* __restrict__ col_src,
    float* __restrict__ hout,
    unsigned short* __restrict__ h16,
    int n, int mode)
{
    __shared__ float lds[4][64 * 17];
    int node = (int)((blockIdx.x * (size_t)blockDim.x + threadIdx.x) >> 6);
    int lane = threadIdx.x & 63;
    int wl = threadIdx.x >> 6;
    if (node >= n) return;
    int h = lane >> 4, j = lane & 15;

    const uint4* q4 = (const uint4*)(qp + (size_t)node * 64 + h * 16);
    uint4 qa = q4[0], qb = q4[1];

    int e0 = row_ptr[node], e1 = row_ptr[node + 1];
    float acc[16];
    #pragma unroll
    for (int c = 0; c < 16; ++c) acc[c] = 0.f;
    float dsum = 0.f;

    for (int eb = e0; eb < e1; eb += 16) {
        int e = eb + j;
        int ec = (e < e1) ? e : (e1 - 1);
        int src = col_src[ec];
        const uint4* kvr = kv4 + (size_t)src * 16 + h * 2;
        uint4 ka = kvr[0], kb = kvr[1];
        uint4 va = kvr[8], vb = kvr[9];
        float s = 0.f;
        s = fdot2_acc(qa.x, ka.x, s);
        s = fdot2_acc(qa.y, ka.y, s);
        s = fdot2_acc(qa.z, ka.z, s);
        s = fdot2_acc(qa.w, ka.w, s);
        s = fdot2_acc(qb.x, kb.x, s);
        s = fdot2_acc(qb.y, kb.y, s);
        s = fdot2_acc(qb.z, kb.z, s);
        s = fdot2_acc(qb.w, kb.w, s);
        float p = (e < e1) ? __expf(s * 0.25f) : 0.f;
        dsum += p;
        unsigned uv[8] = {va.x, va.y, va.z, va.w, vb.x, vb.y, vb.z, vb.w};
        #pragma unroll
        for (int i = 0; i < 8; ++i) {
            __half2 hv = *(__half2*)&uv[i];
            acc[2 * i]     += p * __low2float(hv);
            acc[2 * i + 1] += p * __high2float(hv);
        }
    }

    dsum += __shfl_xor(dsum, 1, 64);
    dsum += __shfl_xor(dsum, 2, 64);
    dsum += __shfl_xor(dsum, 4, 64);
    dsum += __shfl_xor(dsum, 8, 64);
    float inv = 1.f / (dsum + 1e-16f);

    float* L = lds[wl];
    int wb = lane * 17;
    #pragma unroll
    for (int c = 0; c < 16; ++c) L[wb + c] = acc[c];
    __builtin_amdgcn_wave_barrier();
    float sum = 0.f;
    int rb = (h * 16) * 17 + j;
    #pragma unroll
    for (int jj = 0; jj < 16; ++jj) sum += L[rb + jj * 17];

    float outv = sum * inv + sf[(size_t)node * 64 + lane];
    if (mode == 1) {
        outv = fmaxf(outv, 0.f);
        h16[(size_t)node * 64 + lane] = __half_as_ushort(__float2half_rn(outv));
    } else {
        hout[(size_t)node * 64 + lane] = outv;
    }
}

// ---------------- pooling + head ----------------
__global__ void graph_ranges_kernel(const int* __restrict__ bm, int* __restrict__ gstart,
                                    int n, int g) {
    int t = blockIdx.x * blockDim.x + threadIdx.x;
    if (t > g) return;
    if (t == g) { gstart[g] = n; return; }
    int lo = 0, hi = n;
    while (lo < hi) { int mid = (lo + hi) >> 1; if (bm[mid] < t) lo = mid + 1; else hi = mid; }
    gstart[t] = lo;
}

__global__ __launch_bounds__(256) void pool_kernel(
    const float* __restrict__ h, const int* __restrict__ gstart,
    float* __restrict__ pooled)
{
    int g = blockIdx.x;
    int c = threadIdx.x & 63, sub = threadIdx.x >> 6;
    int s = gstart[g], e = gstart[g + 1];
    float sum = 0.f;
    for (int i = s + sub; i < e; i += 4) sum += h[(size_t)i * 64 + c];
    __shared__ float tmp[256];
    tmp[threadIdx.x] = sum;
    __syncthreads();
    if (sub == 0) {
        sum = tmp[c] + tmp[c + 64] + tmp[c + 128] + tmp[c + 192];
        int cnt = e - s;
        pooled[g * 64 + c] = sum / fmaxf((float)cnt, 1.0f);
    }
}

__global__ void head_kernel(const float* __restrict__ pooled,
                            const float* __restrict__ Wl, const float* __restrict__ bl,
                            float* __restrict__ out)
{
    int g = blockIdx.x;
    int lane = threadIdx.x;
    __shared__ float pl[64];
    pl[lane] = pooled[g * 64 + lane];
    __syncthreads();
    float logit = -INFINITY;
    if (lane < NCLS) {
        float acc = bl[lane];
        for (int k = 0; k < 64; ++k) acc += pl[k] * Wl[k * NCLS + lane];
        logit = acc;
    }
    float mx = logit;
    mx = fmaxf(mx, __shfl_xor(mx, 1, 64));
    mx = fmaxf(mx, __shfl_xor(mx, 2, 64));
    mx = fmaxf(mx, __shfl_xor(mx, 4, 64));
    mx = fmaxf(mx, __shfl_xor(mx, 8, 64));
    float ex = (lane < NCLS) ? __expf(logit - mx) : 0.f;
    float sm = ex;
    sm += __shfl_xor(sm, 1, 64);
    sm += __shfl_xor(sm, 2, 64);
    sm += __shfl_xor(sm, 4, 64);
    sm += __shfl_xor(sm, 8, 64);
    if (lane < NCLS) out[g * NCLS + lane] = ex / sm;
}

// ---------------- launch ----------------
extern "C" void kernel_launch(void* const* d_in, const int* in_sizes, int n_in,
                              void* d_out, int out_size, void* d_ws, size_t ws_size,
                              hipStream_t stream) {
    const float* x  = (const float*)d_in[0];
    const int*   ei = (const int*)d_in[1];
    const int*   bm = (const int*)d_in[2];
    const float* W1[4] = {(const float*)d_in[3], (const float*)d_in[5], (const float*)d_in[7], (const float*)d_in[9]};
    const float* B1[4] = {(const float*)d_in[4], (const float*)d_in[6], (const float*)d_in[8], (const float*)d_in[10]};
    const float* W2[4] = {(const float*)d_in[11], (const float*)d_in[13], (const float*)d_in[15], (const float*)d_in[17]};
    const float* B2[4] = {(const float*)d_in[12], (const float*)d_in[14], (const float*)d_in[16], (const float*)d_in[18]};
    const float* W3[4] = {(const float*)d_in[19], (const float*)d_in[21], (const float*)d_in[23], (const float*)d_in[25]};
    const float* B3[4] = {(const float*)d_in[20], (const float*)d_in[22], (const float*)d_in[24], (const float*)d_in[26]};
    const float* Wl = (const float*)d_in[27];
    const float* bl = (const float*)d_in[28];
    float* outp = (float*)d_out;

    // workspace layout
    float* sf     = (float*)d_ws;                                 // NPAD*64 f32
    float* hf     = sf + (size_t)NPAD * 64;                       // NPAD*64 f32
    float* pooled = hf + (size_t)NPAD * 64;                       // NG*64
    unsigned short* qp16 = (unsigned short*)(pooled + NG * 64);   // NPAD*64 fp16
    unsigned short* kvpk = qp16 + (size_t)NPAD * 64;              // NPAD*128 fp16
    unsigned short* xf16 = kvpk + (size_t)NPAD * 128;             // NPAD*128 fp16
    unsigned short* hs16 = xf16 + (size_t)NPAD * 128;             // NPAD*64 fp16
    unsigned short* wt_h = hs16 + (size_t)NPAD * 64;              // 3 * 4*64*128
    unsigned short* wt_l = wt_h + 3 * 4 * 64 * 128;
    int* row_ptr = (int*)(wt_l + 3 * 4 * 64 * 128);               // N+1
    int* fillp   = row_ptr + (N_NODES + 1);                       // N
    int* counts  = fillp + N_NODES;                               // N
    int* excl    = counts + N_NODES;                              // N
    int* bsum    = excl + N_NODES;                                // 256
    int* boff    = bsum + 256;                                    // 256
    int* col_src = boff + 256;                                    // E
    int* gstart  = col_src + N_EDGES;                             // NG+1

    const int* srcp = ei;
    const int* dstp = ei + N_EDGES;

    // CSR build (dst-range partitioned, nt edge streams)
    hipMemsetAsync(counts, 0, N_NODES * sizeof(int), stream);
    hist_part_kernel<<<1024, 256, 0, stream>>>(dstp, counts, N_EDGES);
    scanA_kernel<<<196, 256, 0, stream>>>(counts, excl, bsum, N_NODES);
    scanB_kernel<<<1, 256, 0, stream>>>(bsum, boff, 196);
    scanC_kernel<<<196, 256, 0, stream>>>(excl, boff, row_ptr, fillp, N_NODES);
    scatter_part_kernel<<<1024, 256, 0, stream>>>(srcp, dstp, fillp, col_src, N_EDGES);

    // conversions
    int n4x = N_NODES * F_IN / 4;
    castx_kernel<<<(n4x + 255) / 256, 256, 0, stream>>>(x, xf16, n4x);
    wconv_kernel<<<(4 * 128 * 64 + 255) / 256, 256, 0, stream>>>(
        W1[0], W1[1], W1[2], W1[3], F_IN, wt_h + 0 * 4 * 64 * 128, wt_l + 0 * 4 * 64 * 128);
    wconv_kernel<<<(4 * 64 * 64 + 255) / 256, 256, 0, stream>>>(
        W2[0], W2[1], W2[2], W2[3], HC, wt_h + 1 * 4 * 64 * 128, wt_l + 1 * 4 * 64 * 128);
    wconv_kernel<<<(4 * 64 * 64 + 255) / 256, 256, 0, stream>>>(
        W3[0], W3[1], W3[2], W3[3], HC, wt_h + 2 * 4 * 64 * 128, wt_l + 2 * 4 * 64 * 128);

    int ggrid = 8 * XCHUNK * 4;
    int agrid = (N_NODES + 3) / 4;
    size_t smem1 = (size_t)3 * 64 * F_IN * 2;   // 48 KB
    size_t smem2 = (size_t)3 * 64 * HC * 2;     // 24 KB

    // layer 1
    mfma_gemm_kernel<<<ggrid, 256, smem1, stream>>>(xf16,
        wt_h + 0 * 4 * 64 * 128, wt_l + 0 * 4 * 64 * 128,
        B1[0], B1[1], B1[2], B1[3], qp16, sf, kvpk, N_NODES, F_IN);
    attn_kernel<<<agrid, 256, 0, stream>>>(qp16, sf, (const uint4*)kvpk, row_ptr, col_src,
                                           nullptr, hs16, N_NODES, 1);
    // layer 2
    mfma_gemm_kernel<<<ggrid, 256, smem2, stream>>>(hs16,
        wt_h + 1 * 4 * 64 * 128, wt_l + 1 * 4 * 64 * 128,
        B2[0], B2[1], B2[2], B2[3], qp16, sf, kvpk, N_NODES, HC);
    attn_kernel<<<agrid, 256, 0, stream>>>(qp16, sf, (const uint4*)kvpk, row_ptr, col_src,
                                           nullptr, hs16, N_NODES, 1);
    // layer 3
    mfma_gemm_kernel<<<ggrid, 256, smem2, stream>>>(hs16,
        wt_h + 2 * 4 * 64 * 128, wt_l + 2 * 4 * 64 * 128,
        B3[0], B3[1], B3[2], B3[3], qp16, sf, kvpk, N_NODES, HC);
    attn_kernel<<<agrid, 256, 0, stream>>>(qp16, sf, (const uint4*)kvpk, row_ptr, col_src,
                                           hf, nullptr, N_NODES, 0);

    // pooling + head
    graph_ranges_kernel<<<1, 256, 0, stream>>>(bm, gstart, N_NODES, NG);
    pool_kernel<<<NG, 256, 0, stream>>>(hf, gstart, pooled);
    head_kernel<<<NG, 64, 0, stream>>>(pooled, Wl, bl, outp);
}